// Round 13
// baseline (726.440 us; speedup 1.0000x reference)
//
#include <hip/hip_runtime.h>
#include <stdint.h>

typedef __bf16 bf16x8 __attribute__((ext_vector_type(8)));
typedef __bf16 bf16x4 __attribute__((ext_vector_type(4)));
typedef float  f32x4  __attribute__((ext_vector_type(4)));
typedef unsigned int u32;

__device__ __forceinline__ void gl_lds16(const void* gptr, void* lptr) {
    __builtin_amdgcn_global_load_lds(
        (const __attribute__((address_space(1))) u32*)gptr,
        (__attribute__((address_space(3))) u32*)lptr,
        16, 0, 0);
}

// Branchless tanh-approx GELU (~10 VALU ops: 1 v_exp, 1 v_rcp) vs erff's ~35.
__device__ __forceinline__ float gelu_f(float x) {
    float u = 0.7978845608f * x * (1.0f + 0.044715f * x * x);
    float e = __expf(2.0f * u);
    float t = 1.0f - 2.0f / (e + 1.0f);
    return 0.5f * x * (1.0f + t);
}

#define MEMFENCE __asm__ __volatile__("" ::: "memory")

// ---------------------------------------------------------------------------
// prep_all: merged {build_G | f32_to_bf16 | build_M1 | zero_out} by block range
// ---------------------------------------------------------------------------
__global__ __launch_bounds__(256)
void prep_all(const float* __restrict__ dist, __bf16* __restrict__ G,
              const float* __restrict__ x, __bf16* __restrict__ xb,
              const float* __restrict__ rbfW, const float* __restrict__ rbf_b,
              __bf16* __restrict__ M1, float* __restrict__ out) {
    const int b = blockIdx.x;
    const int t = threadIdx.x;
    if (b < 1024) {
        const int row = b * 32 + (t >> 3);
        const int c0 = (t & 7) * 8;
        const float sp = 12.0f / 49.0f;
        const float coeff = -0.5f / (sp * sp);
        const float d = dist[row];
        bf16x8 v;
#pragma unroll
        for (int q = 0; q < 8; ++q) {
            const int k = c0 + q;
            float val;
            if (k < 50)       { float tt = d - (float)k * sp; val = __expf(coeff * tt * tt); }
            else if (k == 50) val = 1.0f;
            else              val = 0.0f;
            v[q] = (__bf16)val;
        }
        *(bf16x8*)(G + (size_t)row * 64 + c0) = v;
    } else if (b < 1152) {
        const int idx = (b - 1024) * 256 + t;
        float4 v = *(const float4*)(x + idx * 4);
        bf16x4 o;
        o[0] = (__bf16)v.x; o[1] = (__bf16)v.y; o[2] = (__bf16)v.z; o[3] = (__bf16)v.w;
        *(bf16x4*)(xb + idx * 4) = o;
    } else if (b < 1280) {
        const int tt = (b - 1152) * 256 + t;
        const int r = tt >> 8;
        const int c = (tt & 255) * 2;
        float v0 = 0.f, v1 = 0.f;
        if (r < 50)       { v0 = rbfW[r * 512 + c]; v1 = rbfW[r * 512 + c + 1]; }
        else if (r == 50) { v0 = rbf_b[c];          v1 = rbf_b[c + 1]; }
        M1[r * 512 + c] = (__bf16)v0;
        M1[r * 512 + c + 1] = (__bf16)v1;
    } else {
        const int i = (b - 1280) * 256 + t;
        if (i < 770) out[i] = 0.0f;
    }
}

// ---------------------------------------------------------------------------
// transpose_all: fp32 [K][N] -> bf16 [N][K]; z<2: Win (K=1536, branch=z);
// z>=2: Wh (K=1024, zz=z-2, branch=zz/3, layer=zz%3). Grid (24,16,8).
// (r13: Wh shuffle REVERTED — B back in LDS for the 8-phase template)
// ---------------------------------------------------------------------------
__global__ __launch_bounds__(256)
void transpose_all(const float* __restrict__ eWin, const float* __restrict__ fWin,
                   __bf16* __restrict__ eWinT, __bf16* __restrict__ fWinT,
                   const float* __restrict__ eWh, const float* __restrict__ fWh,
                   __bf16* __restrict__ eWhT, __bf16* __restrict__ fWhT) {
    const int z = blockIdx.z;
    int K, branch, l;
    const float* src;
    __bf16* dst;
    if (z < 2) {
        K = 1536; branch = z; l = 0;
        src = branch ? fWin : eWin;
        dst = branch ? fWinT : eWinT;
    } else {
        K = 1024; const int zz = z - 2; branch = zz / 3; l = zz - branch * 3;
        src = (branch ? fWh : eWh) + (size_t)l * 1024 * 1024;
        dst = (branch ? fWhT : eWhT) + (size_t)l * 1024 * 1024;
    }
    const int Ncols = 1024;
    const int bk = blockIdx.x * 64;
    if (bk >= K) return;
    const int bn = blockIdx.y * 64;

    __shared__ float tile[64][65];
    const int tid = threadIdx.x;
    const int tr = tid >> 4;
    const int tc = (tid & 15) * 4;
#pragma unroll
    for (int p = 0; p < 4; ++p) {
        const int r = tr + p * 16;
        float4 v = *(const float4*)&src[(size_t)(bk + r) * Ncols + bn + tc];
        tile[r][tc] = v.x; tile[r][tc + 1] = v.y;
        tile[r][tc + 2] = v.z; tile[r][tc + 3] = v.w;
    }
    __syncthreads();
#pragma unroll
    for (int p = 0; p < 4; ++p) {
        const int rn = tr + p * 16;
        bf16x4 o;
        o[0] = (__bf16)tile[tc + 0][rn];
        o[1] = (__bf16)tile[tc + 1][rn];
        o[2] = (__bf16)tile[tc + 2][rn];
        o[3] = (__bf16)tile[tc + 3][rn];
        *(bf16x4*)&dst[(size_t)(bn + rn) * K + bk + tc] = o;
    }
}

// ---------------------------------------------------------------------------
// 128x128-tile MFMA GEMM (kept for P-merge / WgT dispatches).
// ---------------------------------------------------------------------------
template <int NK, int NBN, int MODE, bool DUAL, int MINW, bool SWZ>
__global__ __launch_bounds__(256, MINW)
void gemm_k(const __bf16* __restrict__ A0, const __bf16* __restrict__ A1,
            const __bf16* __restrict__ B0, const __bf16* __restrict__ B1,
            int lda, int ldb, int ldc,
            const float* __restrict__ bias0, const float* __restrict__ bias1,
            __bf16* __restrict__ C0, __bf16* __restrict__ C1,
            float* __restrict__ Cf0, float* __restrict__ Cf1,
            const float* __restrict__ P0, const float* __restrict__ P1,
            const float* __restrict__ wout0, const float* __restrict__ wout1,
            float* __restrict__ dot0, float* __restrict__ dot1) {
    constexpr int NBS = (NBN == 16) ? 4 : (NBN == 8) ? 3 : 0;
    __shared__ __align__(16) __bf16 As[3][128 * 32];
    __shared__ __align__(16) __bf16 Bs[3][128 * 32];

    const int tid = threadIdx.x;
    int bn, bm, branch = 0;
    if constexpr (SWZ) {
        const int x = blockIdx.x & 7;
        const int slot = blockIdx.x >> 3;
        bn = slot & (NBN - 1);
        int grp = x + ((slot >> NBS) << 3);
        if constexpr (DUAL) {
            const int half = (gridDim.x >> NBS) >> 1;
            branch = (grp >= half);
            if (branch) grp -= half;
        }
        bm = grp;
    } else {
        int f2 = blockIdx.x;
        if constexpr (DUAL) {
            const int half = gridDim.x >> 1;
            branch = (f2 >= half);
            if (branch) f2 -= half;
        }
        bn = f2 & (NBN - 1);
        bm = f2 >> NBS;
    }
    const int w = tid >> 6;
    const int lane = tid & 63;

    const __bf16* Ab = (DUAL && branch) ? A1 : A0;
    const __bf16* Bb = (DUAL && branch) ? B1 : B0;

    const int r0 = tid >> 2;
    const int s0 = tid & 3;
    const char* gA0 = (const char*)Ab + (size_t)(bm * 128 + r0) * lda + s0 * 16;
    const char* gA1 = gA0 + (size_t)64 * lda;
    const char* gB0 = (const char*)Bb + (size_t)(bn * 128 + r0) * ldb + s0 * 16;
    const char* gB1 = gB0 + (size_t)64 * ldb;

    char* lA0 = (char*)&As[0][0] + w * 1024;
    char* lA1 = (char*)&As[1][0] + w * 1024;
    char* lA2 = (char*)&As[2][0] + w * 1024;
    char* lB0 = (char*)&Bs[0][0] + w * 1024;
    char* lB1 = (char*)&Bs[1][0] + w * 1024;
    char* lB2 = (char*)&Bs[2][0] + w * 1024;

    const int wm = (w >> 1) & 1;
    const int wn = w & 1;
    const int lm = lane & 15;
    const int ko = (lane >> 4) << 3;
    const int fo = (wm * 64 + lm) * 32 + ko;
    const int go = (wn * 64 + lm) * 32 + ko;
    const __bf16* pA0 = &As[0][0] + fo;
    const __bf16* pA1 = &As[1][0] + fo;
    const __bf16* pA2 = &As[2][0] + fo;
    const __bf16* pB0 = &Bs[0][0] + go;
    const __bf16* pB1 = &Bs[1][0] + go;
    const __bf16* pB2 = &Bs[2][0] + go;

    f32x4 acc[4][4];
    const f32x4 zero = {0.0f, 0.0f, 0.0f, 0.0f};
#pragma unroll
    for (int i = 0; i < 4; ++i)
#pragma unroll
        for (int j = 0; j < 4; ++j) acc[i][j] = zero;

    auto stage = [&](int buf) {
        char* la = (buf == 0) ? lA0 : (buf == 1) ? lA1 : lA2;
        char* lb = (buf == 0) ? lB0 : (buf == 1) ? lB1 : lB2;
        gl_lds16(gA0, la); gl_lds16(gA1, la + 4096);
        gl_lds16(gB0, lb); gl_lds16(gB1, lb + 4096);
        gA0 += 64; gA1 += 64; gB0 += 64; gB1 += 64;
    };
    auto compute = [&](int buf) {
        const __bf16* pa = (buf == 0) ? pA0 : (buf == 1) ? pA1 : pA2;
        const __bf16* pb = (buf == 0) ? pB0 : (buf == 1) ? pB1 : pB2;
        bf16x8 af[4], bfg[4];
#pragma unroll
        for (int i = 0; i < 4; ++i) {
            af[i]  = *(const bf16x8*)(pa + i * 512);
            bfg[i] = *(const bf16x8*)(pb + i * 512);
        }
#pragma unroll
        for (int mi = 0; mi < 4; ++mi)
#pragma unroll
            for (int ni = 0; ni < 4; ++ni)
                acc[mi][ni] = __builtin_amdgcn_mfma_f32_16x16x32_bf16(
                    af[mi], bfg[ni], acc[mi][ni], 0, 0, 0);
    };
    auto iterstep = [&](int cbuf, int sbuf) {
        MEMFENCE;
        __builtin_amdgcn_s_waitcnt(0xF74);   // vmcnt(4)
        __builtin_amdgcn_s_barrier();
        MEMFENCE;
        compute(cbuf);
        MEMFENCE;
        stage(sbuf);
        MEMFENCE;
    };

    stage(0);
    stage(1);
    constexpr int NIT = NK - 2;
    constexpr int NG = NIT / 3;
    constexpr int NR = NIT % 3;
    for (int g = 0; g < NG; ++g) {
        iterstep(0, 2);
        iterstep(1, 0);
        iterstep(2, 1);
    }
    if constexpr (NR >= 1) iterstep(0, 2);
    if constexpr (NR >= 2) iterstep(1, 0);
    MEMFENCE;
    __builtin_amdgcn_s_waitcnt(0xF74);
    __builtin_amdgcn_s_barrier();
    MEMFENCE;
    compute((NK - 2) % 3);
    MEMFENCE;
    __builtin_amdgcn_s_waitcnt(0xF70);
    __builtin_amdgcn_s_barrier();
    MEMFENCE;
    compute((NK - 1) % 3);

    const int col0 = bn * 128 + wn * 64 + lm;
    const int row0 = bm * 128 + wm * 64 + ((lane >> 4) << 2);
    const int ldaE = lda >> 1;

    float rowdot[16];
    if constexpr (MODE == 1) {
#pragma unroll
        for (int q = 0; q < 16; ++q) rowdot[q] = 0.0f;
    }

    const bool side = (MODE == 2) && (bn >= 8);
    const float* bp = (MODE == 2) ? (side ? bias1 : bias0)
                                  : ((DUAL && branch) ? bias1 : bias0);
    __bf16* Cout = (MODE == 2) ? (side ? C1 : C0)
                               : ((DUAL && branch) ? C1 : C0);
    const float* woutb = (MODE == 1) ? ((DUAL && branch) ? wout1 : wout0) : nullptr;

#pragma unroll
    for (int ni = 0; ni < 4; ++ni) {
        const int gn = col0 + ni * 16;
        const int gnl = (MODE == 2) ? (gn & 1023) : gn;
        float bv = 0.0f;
        if constexpr (MODE <= 2) bv = bp[gnl];
        float wv = 0.0f;
        if constexpr (MODE == 1) wv = woutb[gn];

        float res[16];
        if constexpr (MODE == 0 || MODE == 1) {
#pragma unroll
            for (int mi = 0; mi < 4; ++mi)
#pragma unroll
                for (int rr = 0; rr < 4; ++rr)
                    res[mi * 4 + rr] =
                        (float)Ab[(size_t)(row0 + mi * 16 + rr) * ldaE + gn];
        } else if constexpr (MODE == 2) {
#pragma unroll
            for (int mi = 0; mi < 4; ++mi)
#pragma unroll
                for (int rr = 0; rr < 4; ++rr) {
                    const int gm = row0 + mi * 16 + rr;
                    const int p0row = ((gm >> 8) << 1) | (gm & 1);
                    const int p1row = gm & 255;
                    res[mi * 4 + rr] = P0[(size_t)p0row * 2048 + gn]
                                     + P1[(size_t)p1row * 2048 + gn];
                }
        }
        MEMFENCE;

#pragma unroll
        for (int mi = 0; mi < 4; ++mi) {
#pragma unroll
            for (int rr = 0; rr < 4; ++rr) {
                const int gm = row0 + mi * 16 + rr;
                const float a = acc[mi][ni][rr];
                if constexpr (MODE == 0) {
                    float v = gelu_f(a + bv) + res[mi * 4 + rr];
                    Cout[(size_t)gm * ldc + gn] = (__bf16)v;
                } else if constexpr (MODE == 1) {
                    float v = gelu_f(a + bv) + res[mi * 4 + rr];
                    rowdot[mi * 4 + rr] += v * wv;
                } else if constexpr (MODE == 2) {
                    float v = a + bv + res[mi * 4 + rr];
                    Cout[(size_t)gm * ldc + gnl] = (__bf16)gelu_f(v);
                } else if constexpr (MODE == 3) {
                    float* Cfw = (DUAL && branch) ? Cf1 : Cf0;
                    Cfw[(size_t)gm * ldc + gn] = a;
                } else {
                    C0[(size_t)gm * ldc + gn] = (__bf16)a;
                }
            }
        }
    }

    if constexpr (MODE == 1) {
#pragma unroll
        for (int s = 1; s < 16; s <<= 1)
#pragma unroll
            for (int q = 0; q < 16; ++q) rowdot[q] += __shfl_xor(rowdot[q], s);
        if (lm == 0) {
            float* dotb = (DUAL && branch) ? dot1 : dot0;
            float* dp = dotb + (size_t)(bn * 2 + wn) * 32768 + row0;
#pragma unroll
            for (int q = 0; q < 16; ++q)
                dp[(q >> 2) * 16 + (q & 3)] = rowdot[q];
        }
    }
}

// ---------------------------------------------------------------------------
// gemm256 (256-thr, r11-proven full-LDS body; kept ONLY for L0 / NT==2)
// MODE 2: C = gelu(acc + bias + P0 + P1), side = bn >= NBN/2.
// ---------------------------------------------------------------------------
#define WBAR(imm) do { MEMFENCE; __builtin_amdgcn_s_waitcnt(imm); \
                       __builtin_amdgcn_s_barrier(); MEMFENCE; } while (0)

template <int MODE, bool DUAL, int NBN, int NT, int LDA, int LDB>
__global__ __launch_bounds__(256, 2)
void gemm256(const __bf16* __restrict__ A0, const __bf16* __restrict__ A1,
             const __bf16* __restrict__ B0, const __bf16* __restrict__ B1,
             const float* __restrict__ bias0, const float* __restrict__ bias1,
             __bf16* __restrict__ C0, __bf16* __restrict__ C1,
             const float* __restrict__ wout0, const float* __restrict__ wout1,
             float* __restrict__ dot0, float* __restrict__ dot1,
             const float* __restrict__ P0, const float* __restrict__ P1) {
    constexpr int NBS = (NBN == 16) ? 4 : (NBN == 8) ? 3 : 2;
    __shared__ __align__(16) char ldsbuf[2 * 24576];    // [A 16K | B 8K] x2

    const int tid = threadIdx.x;
    const int nxg = gridDim.x >> 3;
    const int id = (blockIdx.x & 7) * nxg + (blockIdx.x >> 3);
    const int bn = id & (NBN - 1);
    int rest = id >> NBS;
    int branch = 0;
    if constexpr (DUAL) { branch = rest >> 7; rest &= 127; }
    const int bm = rest;

    const __bf16* __restrict__ Ab = (DUAL && branch) ? A1 : A0;
    const __bf16* __restrict__ Bb = (DUAL && branch) ? B1 : B0;

    const int w = tid >> 6;
    const int lane = tid & 63;

    const int srow = tid >> 2;
    const int scol = ((tid & 3) << 4) ^ (((tid >> 3) & 3) << 4);
    const char* gA = (const char*)Ab + (size_t)(bm * 256 + srow) * LDA + scol;
    const char* gB = (const char*)Bb + (size_t)(bn * 128 + srow) * LDB + scol;

    auto stageT = [&](int kt, int buf) {
        const size_t ko = (size_t)kt * 64;
        char* d = ldsbuf + buf * 24576 + w * 1024;
        gl_lds16(gA + ko,             d);
        gl_lds16(gA + ko +  64 * LDA, d + 4096);
        gl_lds16(gA + ko + 128 * LDA, d + 8192);
        gl_lds16(gA + ko + 192 * LDA, d + 12288);
        gl_lds16(gB + ko,             d + 16384);
        gl_lds16(gB + ko +  64 * LDB, d + 20480);
    };

    const int wm = w >> 1, wn = w & 1;
    const int lm = lane & 15, lq = lane >> 4;
    const int swz = ((lm >> 1) & 3) << 4;
    const int rA = (wm * 128 + lm) * 64 + ((lq * 16) ^ swz);
    const int rB = 16384 + (wn * 64 + lm) * 64 + ((lq * 16) ^ swz);

    f32x4 acc[4][8];
    const f32x4 zero = {0.0f, 0.0f, 0.0f, 0.0f};
#pragma unroll
    for (int i = 0; i < 4; ++i)
#pragma unroll
        for (int j = 0; j < 8; ++j) acc[i][j] = zero;

    auto body2 = [&](int kt, int buf, bool dostage) {
        const char* Lb = ldsbuf + buf * 24576;
        MEMFENCE;
        bf16x8 a[8], b[4];
#pragma unroll
        for (int ni = 0; ni < 4; ++ni)
            b[ni] = *(const bf16x8*)(Lb + rB + ni * 1024);
#pragma unroll
        for (int mi = 0; mi < 8; ++mi)
            a[mi] = *(const bf16x8*)(Lb + rA + mi * 1024);
        MEMFENCE;
        __builtin_amdgcn_s_waitcnt(0xC07F);
        MEMFENCE;
        __builtin_amdgcn_s_barrier();
        MEMFENCE;
        if (dostage) stageT(kt + 2, buf);
        MEMFENCE;
        __builtin_amdgcn_s_setprio(1);
#pragma unroll
        for (int ni = 0; ni < 4; ++ni)
#pragma unroll
            for (int mi = 0; mi < 8; ++mi)
                acc[ni][mi] = __builtin_amdgcn_mfma_f32_16x16x32_bf16(
                    b[ni], a[mi], acc[ni][mi], 0, 0, 0);
        __builtin_amdgcn_s_setprio(0);
    };

    // NT == 2 only (L0)
    stageT(0, 0);
    stageT(1, 1);
    WBAR(0xF76); body2(0, 0, false);            // vmcnt(6): buf0 landed
    WBAR(0xF70); body2(1, 1, false);            // vmcnt(0)

    // epilogue (transposed frag)
    const int rowb = bm * 256 + wm * 128 + lm;
    const int nbase = bn * 128 + wn * 64 + lq * 4;

    const bool side = (bn >= (NBN >> 1));
    const float* __restrict__ bp = side ? bias1 : bias0;
    __bf16* __restrict__ Cw = side ? C1 : C0;
    const int nloc = nbase & 1023;
    f32x4 bv[4], p0v[4];
    const size_t p0base = (size_t)((bm << 1) | (lm & 1)) * 2048;
#pragma unroll
    for (int ni = 0; ni < 4; ++ni) {
        bv[ni]  = *(const f32x4*)&bp[nloc + ni * 16];
        p0v[ni] = *(const f32x4*)&P0[p0base + nbase + ni * 16];
    }
#pragma unroll
    for (int mi = 0; mi < 8; ++mi) {
        const int p1row = wm * 128 + mi * 16 + lm;
        f32x4 p1v[4];
#pragma unroll
        for (int ni = 0; ni < 4; ++ni)
            p1v[ni] = *(const f32x4*)&P1[(size_t)p1row * 2048 + nbase + ni * 16];
        MEMFENCE;
        const size_t rb = (size_t)(rowb + mi * 16) * 1024;
#pragma unroll
        for (int ni = 0; ni < 4; ++ni) {
            bf16x4 o;
#pragma unroll
            for (int r = 0; r < 4; ++r)
                o[r] = (__bf16)gelu_f(acc[ni][mi][r] + bv[ni][r] +
                                      p0v[ni][r] + p1v[ni][r]);
            *(bf16x4*)&Cw[rb + nloc + ni * 16] = o;
        }
    }
}

// ---------------------------------------------------------------------------
// gemm8p: the m198/m201 fine-phase template at our shapes. 512 thr (8 waves,
// 2Mx4N), 256x256 tile, K-step 32, 4x32KB rotating bufs, 3-deep prefetch.
// Per K-tile TWO 16-MFMA phases, each: {ds_reads (8 or 4 x b128) + half-tile
// stage issue -> barrier -> lgkmcnt(0) -> setprio(1) 16 MFMA setprio(0) ->
// barrier}. Counted vmcnt(8) ONLY at tile top (taper 8/8/4/0). This is the
// per-phase fine interleave m196/m218 isolated as the +28-41% lever; previous
// rounds ran the documented anti-patterns (2-deep coarse vmcnt, coarse split).
// MODE 0: C = gelu(acc+bias)+A; MODE 1: head rowdot -> dot[(bn*4+wn)*32768].
// ---------------------------------------------------------------------------
template <int MODE, bool DUAL>
__global__ __launch_bounds__(512, 1)
void gemm8p(const __bf16* __restrict__ A0, const __bf16* __restrict__ A1,
            const __bf16* __restrict__ B0, const __bf16* __restrict__ B1,
            const float* __restrict__ bias0, const float* __restrict__ bias1,
            __bf16* __restrict__ C0, __bf16* __restrict__ C1,
            const float* __restrict__ wout0, const float* __restrict__ wout1,
            float* __restrict__ dot0, float* __restrict__ dot1) {
    __shared__ __align__(16) char ldsbuf[4 * 32768];   // buf = [A 16K | B 16K]

    const int tid = threadIdx.x;
    const int nxg = gridDim.x >> 3;
    const int id = (blockIdx.x & 7) * nxg + (blockIdx.x >> 3);  // bijective
    const int bn = id & 3;
    int rest = id >> 2;
    int branch = 0;
    if constexpr (DUAL) { branch = rest >> 7; rest &= 127; }
    const int bm = rest;

    const __bf16* __restrict__ Ab = (DUAL && branch) ? A1 : A0;
    const __bf16* __restrict__ Bb = (DUAL && branch) ? B1 : B0;

    const int w = tid >> 6;
    const int lane = tid & 63;

    // staging: one gl_lds = 512 thr x 16B = 8KB = 128 rows x 64B.
    const int srow = tid >> 2;                          // 0..127
    const int scol = ((tid & 3) << 4) ^ (((tid >> 3) & 3) << 4);
    const char* gA = (const char*)Ab + (size_t)(bm * 256 + srow) * 2048 + scol;
    const char* gB = (const char*)Bb + (size_t)(bn * 256 + srow) * 2048 + scol;

    auto stageA2 = [&](int kt, int buf) {               // A half-tile: 2 loads
        const size_t ko = (size_t)kt * 64;
        char* d = ldsbuf + buf * 32768 + w * 1024;      // wave-uniform dest
        gl_lds16(gA + ko,              d);
        gl_lds16(gA + ko + 128 * 2048, d + 8192);       // rows +128
    };
    auto stageB2 = [&](int kt, int buf) {               // B half-tile: 2 loads
        const size_t ko = (size_t)kt * 64;
        char* d = ldsbuf + buf * 32768 + w * 1024;
        gl_lds16(gB + ko,              d + 16384);
        gl_lds16(gB + ko + 128 * 2048, d + 24576);
    };

    // fragment read addressing (proven swizzle pair; 0 bank conflicts)
    const int wm = w >> 2, wn = w & 3;                  // 2 x 4 waves
    const int lm = lane & 15, lq = lane >> 4;
    const int swz = ((lm >> 1) & 3) << 4;
    const int rA = (wm * 128 + lm) * 64 + ((lq * 16) ^ swz);
    const int rB = 16384 + (wn * 64 + lm) * 64 + ((lq * 16) ^ swz);

    f32x4 acc[4][8];                                    // [ni][mi] transposed
    const f32x4 zero = {0.0f, 0.0f, 0.0f, 0.0f};
#pragma unroll
    for (int i = 0; i < 4; ++i)
#pragma unroll
        for (int j = 0; j < 8; ++j) acc[i][j] = zero;

    // one K-32 tile = 2 fine phases of 16 MFMA each (template micro-structure)
    auto body = [&](int kt, int cbuf, int sbuf, bool dostage) {
        const char* Lb = ldsbuf + cbuf * 32768;
        bf16x8 a[8], b[4];
        MEMFENCE;
        // ---- phase 1: b[0..3] + a[0..3] reads, A-half stage of tile kt+3
#pragma unroll
        for (int ni = 0; ni < 4; ++ni)
            b[ni] = *(const bf16x8*)(Lb + rB + ni * 1024);
#pragma unroll
        for (int mi = 0; mi < 4; ++mi)
            a[mi] = *(const bf16x8*)(Lb + rA + mi * 1024);
        if (dostage) stageA2(kt + 3, sbuf);
        MEMFENCE;
        __builtin_amdgcn_s_barrier();
        MEMFENCE;
        __builtin_amdgcn_s_waitcnt(0xC07F);             // lgkmcnt(0)
        MEMFENCE;
        __builtin_amdgcn_s_setprio(1);
#pragma unroll
        for (int ni = 0; ni < 4; ++ni)
#pragma unroll
            for (int mi = 0; mi < 4; ++mi)
                acc[ni][mi] = __builtin_amdgcn_mfma_f32_16x16x32_bf16(
                    b[ni], a[mi], acc[ni][mi], 0, 0, 0);
        __builtin_amdgcn_s_setprio(0);
        MEMFENCE;
        __builtin_amdgcn_s_barrier();
        MEMFENCE;
        // ---- phase 2: a[4..7] reads, B-half stage of tile kt+3
#pragma unroll
        for (int mi = 4; mi < 8; ++mi)
            a[mi] = *(const bf16x8*)(Lb + rA + mi * 1024);
        if (dostage) stageB2(kt + 3, sbuf);
        MEMFENCE;
        __builtin_amdgcn_s_barrier();
        MEMFENCE;
        __builtin_amdgcn_s_waitcnt(0xC07F);             // lgkmcnt(0)
        MEMFENCE;
        __builtin_amdgcn_s_setprio(1);
#pragma unroll
        for (int ni = 0; ni < 4; ++ni)
#pragma unroll
            for (int mi = 4; mi < 8; ++mi)
                acc[ni][mi] = __builtin_amdgcn_mfma_f32_16x16x32_bf16(
                    b[ni], a[mi], acc[ni][mi], 0, 0, 0);
        __builtin_amdgcn_s_setprio(0);
        // closing vmcnt+barrier supplied by caller (tile-top of kt+1)
    };

    // prologue: 3-deep prefetch (A+B per tile = 4 loads/wave-slice)
    stageA2(0, 0); stageB2(0, 0);
    stageA2(1, 1); stageB2(1, 1);
    stageA2(2, 2); stageB2(2, 2);
    for (int g = 0; g < 7; ++g) {                       // kt = 0..27
        const int k0 = g * 4;
        WBAR(0xF78); body(k0 + 0, 0, 3, true);          // vmcnt(8): tile in
        WBAR(0xF78); body(k0 + 1, 1, 0, true);
        WBAR(0xF78); body(k0 + 2, 2, 1, true);
        WBAR(0xF78); body(k0 + 3, 3, 2, true);
    }
    WBAR(0xF78); body(28, 0, 3, true);                  // stages tile 31
    WBAR(0xF78); body(29, 1, 0, false);
    WBAR(0xF74); body(30, 2, 1, false);                 // vmcnt(4)
    WBAR(0xF70); body(31, 3, 2, false);                 // vmcnt(0)

    // ---- epilogue (transposed frag): lane (lm,lq), frag (ni,mi) holds
    // C[m = bm*256+wm*128+mi*16+lm][n = bn*256+wn*64+ni*16+lq*4+r]
    const int rowb = bm * 256 + wm * 128 + lm;
    const int nbase = bn * 256 + wn * 64 + lq * 4;

    const float* __restrict__ bp = (DUAL && branch) ? bias1 : bias0;
    f32x4 bv[4];
#pragma unroll
    for (int ni = 0; ni < 4; ++ni)
        bv[ni] = *(const f32x4*)&bp[nbase + ni * 16];

    if constexpr (MODE == 0) {
        __bf16* __restrict__ Cw = (DUAL && branch) ? C1 : C0;
#pragma unroll
        for (int mi = 0; mi < 8; ++mi) {
            const size_t rb = (size_t)(rowb + mi * 16) * 1024;
            bf16x4 res[4];
#pragma unroll
            for (int ni = 0; ni < 4; ++ni)
                res[ni] = *(const bf16x4*)&Ab[rb + nbase + ni * 16];
            MEMFENCE;
#pragma unroll
            for (int ni = 0; ni < 4; ++ni) {
                bf16x4 o;
#pragma unroll
                for (int r = 0; r < 4; ++r)
                    o[r] = (__bf16)(gelu_f(acc[ni][mi][r] + bv[ni][r]) +
                                    (float)res[ni][r]);
                *(bf16x4*)&Cw[rb + nbase + ni * 16] = o;
            }
        }
    } else {
        const float* __restrict__ wb = (DUAL && branch) ? wout1 : wout0;
        f32x4 wv[4];
#pragma unroll
        for (int ni = 0; ni < 4; ++ni)
            wv[ni] = *(const f32x4*)&wb[nbase + ni * 16];
        float rd[8];
#pragma unroll
        for (int q = 0; q < 8; ++q) rd[q] = 0.0f;
#pragma unroll
        for (int mi = 0; mi < 8; ++mi) {
            const size_t rb = (size_t)(rowb + mi * 16) * 1024;
            bf16x4 res[4];
#pragma unroll
            for (int ni = 0; ni < 4; ++ni)
                res[ni] = *(const bf16x4*)&Ab[rb + nbase + ni * 16];
            MEMFENCE;
#pragma unroll
            for (int ni = 0; ni < 4; ++ni)
#pragma unroll
                for (int r = 0; r < 4; ++r) {
                    float v = gelu_f(acc[ni][mi][r] + bv[ni][r]) +
                              (float)res[ni][r];
                    rd[mi] += v * wv[ni][r];
                }
        }
#pragma unroll
        for (int mi = 0; mi < 8; ++mi) {
            rd[mi] += __shfl_xor(rd[mi], 16);
            rd[mi] += __shfl_xor(rd[mi], 32);
        }
        if (lq == 0) {
            float* __restrict__ db = (DUAL && branch) ? dot1 : dot0;
            float* dp = db + (size_t)(bn * 4 + wn) * 32768 + bm * 256 + wm * 128;
#pragma unroll
            for (int mi = 0; mi < 8; ++mi)
                dp[mi * 16 + lm] = rd[mi];
        }
    }
}

// ---------------------------------------------------------------------------
// finalize: sum 16 (bn,wn)-partials per row; block = (b,j), reduce over i
// ---------------------------------------------------------------------------
__global__ __launch_bounds__(128)
void finalize(const float* __restrict__ dot_e, const float* __restrict__ dot_f,
              const float* __restrict__ eb, const float* __restrict__ fb,
              const float* __restrict__ vec, float* __restrict__ out) {
    const int bj = blockIdx.x;
    const int bb = bj >> 7, jj = bj & 127;
    const int i = threadIdx.x;
    const int m = (i * 128 + jj) * 2 + bb;
    float e = eb[0], f = fb[0];
#pragma unroll
    for (int s = 0; s < 16; ++s) {
        e += dot_e[(size_t)s * 32768 + m];
        f += dot_f[(size_t)s * 32768 + m];
    }
    f *= (1.0f / 60.0f);
    float fx = f * vec[(size_t)m * 3 + 0];
    float fy = f * vec[(size_t)m * 3 + 1];
    float fz = f * vec[(size_t)m * 3 + 2];
#pragma unroll
    for (int off = 32; off > 0; off >>= 1) {
        e  += __shfl_down(e, off);
        fx += __shfl_down(fx, off);
        fy += __shfl_down(fy, off);
        fz += __shfl_down(fz, off);
    }
    __shared__ float red[2][4];
    const int wv = i >> 6, lane = i & 63;
    if (lane == 0) { red[wv][0] = e; red[wv][1] = fx; red[wv][2] = fy; red[wv][3] = fz; }
    __syncthreads();
    if (i == 0) {
        atomicAdd(&out[bb], (red[0][0] + red[1][0]) * (1.0f / 3600.0f));
        float* fo = out + 2 + bj * 3;
        fo[0] = red[0][1] + red[1][1];
        fo[1] = red[0][2] + red[1][2];
        fo[2] = red[0][3] + red[1][3];
    }
}

// ---------------------------------------------------------------------------
extern "C" void kernel_launch(void* const* d_in, const int* in_sizes, int n_in,
                              void* d_out, int out_size, void* d_ws, size_t ws_size,
                              hipStream_t stream) {
    const float* x     = (const float*)d_in[0];
    const float* dist  = (const float*)d_in[1];
    const float* vec   = (const float*)d_in[2];
    const float* rbfW  = (const float*)d_in[4];
    const float* rbf_b = (const float*)d_in[5];
    const float* eWin  = (const float*)d_in[6];
    const float* ebin  = (const float*)d_in[7];
    const float* eWh   = (const float*)d_in[8];
    const float* ebh   = (const float*)d_in[9];
    const float* eWout = (const float*)d_in[10];
    const float* ebout = (const float*)d_in[11];
    const float* fWin  = (const float*)d_in[12];
    const float* fbin  = (const float*)d_in[13];
    const float* fWh   = (const float*)d_in[14];
    const float* fbh   = (const float*)d_in[15];
    const float* fWout = (const float*)d_in[16];
    const float* fbout = (const float*)d_in[17];
    float* out = (float*)d_out;

    // workspace carve (3-slab, ~234 MB)
    char* p = (char*)d_ws;
    __bf16* WinTcat = (__bf16*)p;
    __bf16* eWinT = WinTcat;          p += (size_t)1024 * 1536 * 2;
    __bf16* fWinT = (__bf16*)p;       p += (size_t)1024 * 1536 * 2;
    __bf16* eWhT0 = (__bf16*)p;       p += (size_t)3 * 1024 * 1024 * 2;
    __bf16* fWhT0 = (__bf16*)p;       p += (size_t)3 * 1024 * 1024 * 2;
    __bf16* xb  = (__bf16*)p;         p += (size_t)256 * 512 * 2;
    __bf16* M1  = (__bf16*)p;         p += (size_t)128 * 512 * 2;
    __bf16* WgT = (__bf16*)p;         p += (size_t)2048 * 128 * 2;
    __bf16* G   = (__bf16*)p;         p += (size_t)32768 * 64 * 2;
    float* P0   = (float*)p;          p += (size_t)256 * 2048 * 4;
    float* P1   = (float*)p;          p += (size_t)256 * 2048 * 4;
    float* dot_e = (float*)p;         p += (size_t)16 * 32768 * 4;
    float* dot_f = (float*)p;         p += (size_t)16 * 32768 * 4;
    const size_t SLAB = (size_t)32768 * 1024 * 2;   // 64 MB
    __bf16* he0 = (__bf16*)p;         p += SLAB;
    __bf16* hf0 = (__bf16*)p;         p += SLAB;
    __bf16* hA  = (__bf16*)p;         p += SLAB;    // shared ping-pong slab

    // merged prep: build_G | x->xb | build_M1 | zero_out
    prep_all<<<dim3(1284), dim3(256), 0, stream>>>(
        dist, G, x, xb, rbfW, rbf_b, M1, out);
    // merged transposes: Win + Wh, both plain [N][K]
    transpose_all<<<dim3(24, 16, 8), dim3(256), 0, stream>>>(
        eWin, fWin, eWinT, fWinT, eWh, fWh, eWhT0, fWhT0);

    const dim3 blk(256);
    // P0|P1 merged: x(256x512) @ Win[0:512) / [512:1024) -> f32 (256x2048)
    gemm_k<16, 16, 3, true, 3, false><<<dim3(64), blk, 0, stream>>>(
        xb, xb, WinTcat, WinTcat + 512, 1024, 3072, 2048,
        nullptr, nullptr, nullptr, nullptr, P0, P1,
        nullptr, nullptr, nullptr, nullptr, nullptr, nullptr);
    // WgT(2048x128) = WinTcat[:,1024:1536] @ M1^T (bf16 raw)
    gemm_k<16, 1, 4, false, 3, false><<<dim3(16), blk, 0, stream>>>(
        WinTcat + 1024, nullptr, M1, nullptr, 3072, 1024, 128,
        nullptr, nullptr, WgT, nullptr, nullptr, nullptr,
        nullptr, nullptr, nullptr, nullptr, nullptr, nullptr);

    // layer 0 (256-thr full-LDS path): he0|hf0 = gelu(G@WgT + bias + P0 + P1)
    gemm256<2, false, 16, 2, 128, 256><<<dim3(2048), blk, 0, stream>>>(
        G, nullptr, WgT, nullptr, ebin, fbin, he0, hf0,
        nullptr, nullptr, nullptr, nullptr, P0, P1);

    const dim3 blk512(512);
    // hidden layers, branch-serial, fine-phase template: grid 512 (128m x 4n)
    gemm8p<0, false><<<dim3(512), blk512, 0, stream>>>(
        he0, nullptr, eWhT0, nullptr, ebh + 0, nullptr,
        hA, nullptr, nullptr, nullptr, nullptr, nullptr);
    gemm8p<0, false><<<dim3(512), blk512, 0, stream>>>(
        hA, nullptr, eWhT0 + (size_t)1048576, nullptr, ebh + 1024, nullptr,
        he0, nullptr, nullptr, nullptr, nullptr, nullptr);
    gemm8p<0, false><<<dim3(512), blk512, 0, stream>>>(
        hf0, nullptr, fWhT0, nullptr, fbh + 0, nullptr,
        hA, nullptr, nullptr, nullptr, nullptr, nullptr);
    gemm8p<0, false><<<dim3(512), blk512, 0, stream>>>(
        hA, nullptr, fWhT0 + (size_t)1048576, nullptr, fbh + 1024, nullptr,
        hf0, nullptr, nullptr, nullptr, nullptr, nullptr);
    // merged DUAL head (writes only 4MB dot buffers): grid 1024
    gemm8p<1, true><<<dim3(1024), blk512, 0, stream>>>(
        he0, hf0, eWhT0 + (size_t)2 * 1048576, fWhT0 + (size_t)2 * 1048576,
        ebh + 2048, fbh + 2048, nullptr, nullptr,
        eWout, fWout, dot_e, dot_f);

    finalize<<<dim3(256), dim3(128), 0, stream>>>(dot_e, dot_f, ebout, fbout, vec, out);
}

// Round 14
// 681.995 us; speedup vs baseline: 1.0652x; 1.0652x over previous
//
#include <hip/hip_runtime.h>
#include <stdint.h>

typedef __bf16 bf16x8 __attribute__((ext_vector_type(8)));
typedef __bf16 bf16x4 __attribute__((ext_vector_type(4)));
typedef float  f32x4  __attribute__((ext_vector_type(4)));
typedef unsigned int u32;

__device__ __forceinline__ void gl_lds16(const void* gptr, void* lptr) {
    __builtin_amdgcn_global_load_lds(
        (const __attribute__((address_space(1))) u32*)gptr,
        (__attribute__((address_space(3))) u32*)lptr,
        16, 0, 0);
}

// Branchless tanh-approx GELU (~10 VALU ops: 1 v_exp, 1 v_rcp) vs erff's ~35.
__device__ __forceinline__ float gelu_f(float x) {
    float u = 0.7978845608f * x * (1.0f + 0.044715f * x * x);
    float e = __expf(2.0f * u);
    float t = 1.0f - 2.0f / (e + 1.0f);
    return 0.5f * x * (1.0f + t);
}

#define MEMFENCE __asm__ __volatile__("" ::: "memory")

// ---------------------------------------------------------------------------
// prep_all: merged {build_G | f32_to_bf16 | build_M1 | zero_out} by block range
// ---------------------------------------------------------------------------
__global__ __launch_bounds__(256)
void prep_all(const float* __restrict__ dist, __bf16* __restrict__ G,
              const float* __restrict__ x, __bf16* __restrict__ xb,
              const float* __restrict__ rbfW, const float* __restrict__ rbf_b,
              __bf16* __restrict__ M1, float* __restrict__ out) {
    const int b = blockIdx.x;
    const int t = threadIdx.x;
    if (b < 1024) {
        const int row = b * 32 + (t >> 3);
        const int c0 = (t & 7) * 8;
        const float sp = 12.0f / 49.0f;
        const float coeff = -0.5f / (sp * sp);
        const float d = dist[row];
        bf16x8 v;
#pragma unroll
        for (int q = 0; q < 8; ++q) {
            const int k = c0 + q;
            float val;
            if (k < 50)       { float tt = d - (float)k * sp; val = __expf(coeff * tt * tt); }
            else if (k == 50) val = 1.0f;
            else              val = 0.0f;
            v[q] = (__bf16)val;
        }
        *(bf16x8*)(G + (size_t)row * 64 + c0) = v;
    } else if (b < 1152) {
        const int idx = (b - 1024) * 256 + t;
        float4 v = *(const float4*)(x + idx * 4);
        bf16x4 o;
        o[0] = (__bf16)v.x; o[1] = (__bf16)v.y; o[2] = (__bf16)v.z; o[3] = (__bf16)v.w;
        *(bf16x4*)(xb + idx * 4) = o;
    } else if (b < 1280) {
        const int tt = (b - 1152) * 256 + t;
        const int r = tt >> 8;
        const int c = (tt & 255) * 2;
        float v0 = 0.f, v1 = 0.f;
        if (r < 50)       { v0 = rbfW[r * 512 + c]; v1 = rbfW[r * 512 + c + 1]; }
        else if (r == 50) { v0 = rbf_b[c];          v1 = rbf_b[c + 1]; }
        M1[r * 512 + c] = (__bf16)v0;
        M1[r * 512 + c + 1] = (__bf16)v1;
    } else {
        const int i = (b - 1280) * 256 + t;
        if (i < 770) out[i] = 0.0f;
    }
}

// ---------------------------------------------------------------------------
// transpose_all: fp32 [K][N] -> z<2: Win bf16 [N][K] (K=1536, branch=z);
// z>=2: Wh SHUFFLED to fragment order for direct-B GEMM:
//   elem B[k][n] -> Bshuf[ ((n>>4)*32 + (k>>5))*512 + lane*8 + (k&7) ],
//   lane = (n&15) | (((k>>3)&3)<<4)   (1KB per (col16,ktile) fragment)
// ---------------------------------------------------------------------------
__global__ __launch_bounds__(256)
void transpose_all(const float* __restrict__ eWin, const float* __restrict__ fWin,
                   __bf16* __restrict__ eWinT, __bf16* __restrict__ fWinT,
                   const float* __restrict__ eWh, const float* __restrict__ fWh,
                   __bf16* __restrict__ eWhT, __bf16* __restrict__ fWhT) {
    const int z = blockIdx.z;
    int K, branch, l;
    const float* src;
    __bf16* dst;
    if (z < 2) {
        K = 1536; branch = z; l = 0;
        src = branch ? fWin : eWin;
        dst = branch ? fWinT : eWinT;
    } else {
        K = 1024; const int zz = z - 2; branch = zz / 3; l = zz - branch * 3;
        src = (branch ? fWh : eWh) + (size_t)l * 1024 * 1024;
        dst = (branch ? fWhT : eWhT) + (size_t)l * 1024 * 1024;
    }
    const int Ncols = 1024;
    const int bk = blockIdx.x * 64;
    if (bk >= K) return;
    const int bn = blockIdx.y * 64;

    __shared__ float tile[64][65];
    const int tid = threadIdx.x;
    const int tr = tid >> 4;
    const int tc = (tid & 15) * 4;
#pragma unroll
    for (int p = 0; p < 4; ++p) {
        const int r = tr + p * 16;
        float4 v = *(const float4*)&src[(size_t)(bk + r) * Ncols + bn + tc];
        tile[r][tc] = v.x; tile[r][tc + 1] = v.y;
        tile[r][tc + 2] = v.z; tile[r][tc + 3] = v.w;
    }
    __syncthreads();
#pragma unroll
    for (int p = 0; p < 4; ++p) {
        const int rn = tr + p * 16;
        bf16x4 o;
        o[0] = (__bf16)tile[tc + 0][rn];
        o[1] = (__bf16)tile[tc + 1][rn];
        o[2] = (__bf16)tile[tc + 2][rn];
        o[3] = (__bf16)tile[tc + 3][rn];
        if (z < 2) {
            *(bf16x4*)&dst[(size_t)(bn + rn) * K + bk + tc] = o;
        } else {
            const int n = bn + rn, k0 = bk + tc;   // 4 consecutive k, same lane
            const size_t off =
                (size_t)((n >> 4) * 32 + (k0 >> 5)) * 1024 +
                (size_t)((n & 15) | (((k0 >> 3) & 3) << 4)) * 16 +
                (size_t)(k0 & 7) * 2;
            *(bf16x4*)((char*)dst + off) = o;
        }
    }
}

// ---------------------------------------------------------------------------
// 128x128-tile MFMA GEMM (kept for P-merge / WgT dispatches).
// ---------------------------------------------------------------------------
template <int NK, int NBN, int MODE, bool DUAL, int MINW, bool SWZ>
__global__ __launch_bounds__(256, MINW)
void gemm_k(const __bf16* __restrict__ A0, const __bf16* __restrict__ A1,
            const __bf16* __restrict__ B0, const __bf16* __restrict__ B1,
            int lda, int ldb, int ldc,
            const float* __restrict__ bias0, const float* __restrict__ bias1,
            __bf16* __restrict__ C0, __bf16* __restrict__ C1,
            float* __restrict__ Cf0, float* __restrict__ Cf1,
            const float* __restrict__ P0, const float* __restrict__ P1,
            const float* __restrict__ wout0, const float* __restrict__ wout1,
            float* __restrict__ dot0, float* __restrict__ dot1) {
    constexpr int NBS = (NBN == 16) ? 4 : (NBN == 8) ? 3 : 0;
    __shared__ __align__(16) __bf16 As[3][128 * 32];
    __shared__ __align__(16) __bf16 Bs[3][128 * 32];

    const int tid = threadIdx.x;
    int bn, bm, branch = 0;
    if constexpr (SWZ) {
        const int x = blockIdx.x & 7;
        const int slot = blockIdx.x >> 3;
        bn = slot & (NBN - 1);
        int grp = x + ((slot >> NBS) << 3);
        if constexpr (DUAL) {
            const int half = (gridDim.x >> NBS) >> 1;
            branch = (grp >= half);
            if (branch) grp -= half;
        }
        bm = grp;
    } else {
        int f2 = blockIdx.x;
        if constexpr (DUAL) {
            const int half = gridDim.x >> 1;
            branch = (f2 >= half);
            if (branch) f2 -= half;
        }
        bn = f2 & (NBN - 1);
        bm = f2 >> NBS;
    }
    const int w = tid >> 6;
    const int lane = tid & 63;

    const __bf16* Ab = (DUAL && branch) ? A1 : A0;
    const __bf16* Bb = (DUAL && branch) ? B1 : B0;

    const int r0 = tid >> 2;
    const int s0 = tid & 3;
    const char* gA0 = (const char*)Ab + (size_t)(bm * 128 + r0) * lda + s0 * 16;
    const char* gA1 = gA0 + (size_t)64 * lda;
    const char* gB0 = (const char*)Bb + (size_t)(bn * 128 + r0) * ldb + s0 * 16;
    const char* gB1 = gB0 + (size_t)64 * ldb;

    char* lA0 = (char*)&As[0][0] + w * 1024;
    char* lA1 = (char*)&As[1][0] + w * 1024;
    char* lA2 = (char*)&As[2][0] + w * 1024;
    char* lB0 = (char*)&Bs[0][0] + w * 1024;
    char* lB1 = (char*)&Bs[1][0] + w * 1024;
    char* lB2 = (char*)&Bs[2][0] + w * 1024;

    const int wm = (w >> 1) & 1;
    const int wn = w & 1;
    const int lm = lane & 15;
    const int ko = (lane >> 4) << 3;
    const int fo = (wm * 64 + lm) * 32 + ko;
    const int go = (wn * 64 + lm) * 32 + ko;
    const __bf16* pA0 = &As[0][0] + fo;
    const __bf16* pA1 = &As[1][0] + fo;
    const __bf16* pA2 = &As[2][0] + fo;
    const __bf16* pB0 = &Bs[0][0] + go;
    const __bf16* pB1 = &Bs[1][0] + go;
    const __bf16* pB2 = &Bs[2][0] + go;

    f32x4 acc[4][4];
    const f32x4 zero = {0.0f, 0.0f, 0.0f, 0.0f};
#pragma unroll
    for (int i = 0; i < 4; ++i)
#pragma unroll
        for (int j = 0; j < 4; ++j) acc[i][j] = zero;

    auto stage = [&](int buf) {
        char* la = (buf == 0) ? lA0 : (buf == 1) ? lA1 : lA2;
        char* lb = (buf == 0) ? lB0 : (buf == 1) ? lB1 : lB2;
        gl_lds16(gA0, la); gl_lds16(gA1, la + 4096);
        gl_lds16(gB0, lb); gl_lds16(gB1, lb + 4096);
        gA0 += 64; gA1 += 64; gB0 += 64; gB1 += 64;
    };
    auto compute = [&](int buf) {
        const __bf16* pa = (buf == 0) ? pA0 : (buf == 1) ? pA1 : pA2;
        const __bf16* pb = (buf == 0) ? pB0 : (buf == 1) ? pB1 : pB2;
        bf16x8 af[4], bfg[4];
#pragma unroll
        for (int i = 0; i < 4; ++i) {
            af[i]  = *(const bf16x8*)(pa + i * 512);
            bfg[i] = *(const bf16x8*)(pb + i * 512);
        }
#pragma unroll
        for (int mi = 0; mi < 4; ++mi)
#pragma unroll
            for (int ni = 0; ni < 4; ++ni)
                acc[mi][ni] = __builtin_amdgcn_mfma_f32_16x16x32_bf16(
                    af[mi], bfg[ni], acc[mi][ni], 0, 0, 0);
    };
    auto iterstep = [&](int cbuf, int sbuf) {
        MEMFENCE;
        __builtin_amdgcn_s_waitcnt(0xF74);   // vmcnt(4)
        __builtin_amdgcn_s_barrier();
        MEMFENCE;
        compute(cbuf);
        MEMFENCE;
        stage(sbuf);
        MEMFENCE;
    };

    stage(0);
    stage(1);
    constexpr int NIT = NK - 2;
    constexpr int NG = NIT / 3;
    constexpr int NR = NIT % 3;
    for (int g = 0; g < NG; ++g) {
        iterstep(0, 2);
        iterstep(1, 0);
        iterstep(2, 1);
    }
    if constexpr (NR >= 1) iterstep(0, 2);
    if constexpr (NR >= 2) iterstep(1, 0);
    MEMFENCE;
    __builtin_amdgcn_s_waitcnt(0xF74);
    __builtin_amdgcn_s_barrier();
    MEMFENCE;
    compute((NK - 2) % 3);
    MEMFENCE;
    __builtin_amdgcn_s_waitcnt(0xF70);
    __builtin_amdgcn_s_barrier();
    MEMFENCE;
    compute((NK - 1) % 3);

    const int col0 = bn * 128 + wn * 64 + lm;
    const int row0 = bm * 128 + wm * 64 + ((lane >> 4) << 2);
    const int ldaE = lda >> 1;

    float rowdot[16];
    if constexpr (MODE == 1) {
#pragma unroll
        for (int q = 0; q < 16; ++q) rowdot[q] = 0.0f;
    }

    const bool side = (MODE == 2) && (bn >= 8);
    const float* bp = (MODE == 2) ? (side ? bias1 : bias0)
                                  : ((DUAL && branch) ? bias1 : bias0);
    __bf16* Cout = (MODE == 2) ? (side ? C1 : C0)
                               : ((DUAL && branch) ? C1 : C0);
    const float* woutb = (MODE == 1) ? ((DUAL && branch) ? wout1 : wout0) : nullptr;

#pragma unroll
    for (int ni = 0; ni < 4; ++ni) {
        const int gn = col0 + ni * 16;
        const int gnl = (MODE == 2) ? (gn & 1023) : gn;
        float bv = 0.0f;
        if constexpr (MODE <= 2) bv = bp[gnl];
        float wv = 0.0f;
        if constexpr (MODE == 1) wv = woutb[gn];

        float res[16];
        if constexpr (MODE == 0 || MODE == 1) {
#pragma unroll
            for (int mi = 0; mi < 4; ++mi)
#pragma unroll
                for (int rr = 0; rr < 4; ++rr)
                    res[mi * 4 + rr] =
                        (float)Ab[(size_t)(row0 + mi * 16 + rr) * ldaE + gn];
        } else if constexpr (MODE == 2) {
#pragma unroll
            for (int mi = 0; mi < 4; ++mi)
#pragma unroll
                for (int rr = 0; rr < 4; ++rr) {
                    const int gm = row0 + mi * 16 + rr;
                    const int p0row = ((gm >> 8) << 1) | (gm & 1);
                    const int p1row = gm & 255;
                    res[mi * 4 + rr] = P0[(size_t)p0row * 2048 + gn]
                                     + P1[(size_t)p1row * 2048 + gn];
                }
        }
        MEMFENCE;

#pragma unroll
        for (int mi = 0; mi < 4; ++mi) {
#pragma unroll
            for (int rr = 0; rr < 4; ++rr) {
                const int gm = row0 + mi * 16 + rr;
                const float a = acc[mi][ni][rr];
                if constexpr (MODE == 0) {
                    float v = gelu_f(a + bv) + res[mi * 4 + rr];
                    Cout[(size_t)gm * ldc + gn] = (__bf16)v;
                } else if constexpr (MODE == 1) {
                    float v = gelu_f(a + bv) + res[mi * 4 + rr];
                    rowdot[mi * 4 + rr] += v * wv;
                } else if constexpr (MODE == 2) {
                    float v = a + bv + res[mi * 4 + rr];
                    Cout[(size_t)gm * ldc + gnl] = (__bf16)gelu_f(v);
                } else if constexpr (MODE == 3) {
                    float* Cfw = (DUAL && branch) ? Cf1 : Cf0;
                    Cfw[(size_t)gm * ldc + gn] = a;
                } else {
                    C0[(size_t)gm * ldc + gn] = (__bf16)a;
                }
            }
        }
    }

    if constexpr (MODE == 1) {
#pragma unroll
        for (int s = 1; s < 16; s <<= 1)
#pragma unroll
            for (int q = 0; q < 16; ++q) rowdot[q] += __shfl_xor(rowdot[q], s);
        if (lm == 0) {
            float* dotb = (DUAL && branch) ? dot1 : dot0;
            float* dp = dotb + (size_t)(bn * 2 + wn) * 32768 + row0;
#pragma unroll
            for (int q = 0; q < 16; ++q)
                dp[(q >> 2) * 16 + (q & 3)] = rowdot[q];
        }
    }
}

// ---------------------------------------------------------------------------
// gemm256 v12 (session best, locked): 256(M)x128(N) tile, 256 threads
// (4 waves 2x2), BK=32.
// BD=true (hidden/head): B DIRECT from preshuffled global (L2-resident) into
//   MFMA regs, 2-deep pipelined; LDS holds A ONLY (2x16KB). Removing B from
//   LDS cut LDS traffic ~25% -> best measured MfmaUtil 37% / head 167us.
//   Issue order/iter: 4x gl_lds A(kt+2) ... 4x global B(kt+2); counted
//   vmcnt(8) at tile top == {A(kt),B(kt)} retired.
// BD=false (L0, NT==2): r11-proven full-LDS body2 (2x24KB, B in LDS).
// MODE 0: C = gelu(acc+bias)+A; MODE 1: head rowdot -> dot[(bn*2+wn)*32768];
// MODE 2: L0 (bias + P0 + P1, side = bn >= NBN/2).
// ---------------------------------------------------------------------------
#define WBAR(imm) do { MEMFENCE; __builtin_amdgcn_s_waitcnt(imm); \
                       __builtin_amdgcn_s_barrier(); MEMFENCE; } while (0)

template <int MODE, bool DUAL, int NBN, int NT, int LDA, int LDB, bool BD>
__global__ __launch_bounds__(256, 2)
void gemm256(const __bf16* __restrict__ A0, const __bf16* __restrict__ A1,
             const __bf16* __restrict__ B0, const __bf16* __restrict__ B1,
             const float* __restrict__ bias0, const float* __restrict__ bias1,
             __bf16* __restrict__ C0, __bf16* __restrict__ C1,
             const float* __restrict__ wout0, const float* __restrict__ wout1,
             float* __restrict__ dot0, float* __restrict__ dot1,
             const float* __restrict__ P0, const float* __restrict__ P1) {
    constexpr int NBS = (NBN == 16) ? 4 : (NBN == 8) ? 3 : 2;
    constexpr int BUFSZ = BD ? 16384 : 24576;
    __shared__ __align__(16) char ldsbuf[2 * BUFSZ];

    const int tid = threadIdx.x;
    const int nxg = gridDim.x >> 3;                 // blocks per XCD slot
    const int id = (blockIdx.x & 7) * nxg + (blockIdx.x >> 3);  // bijective
    const int bn = id & (NBN - 1);
    int rest = id >> NBS;
    int branch = 0;
    if constexpr (DUAL) { branch = rest >> 7; rest &= 127; }
    const int bm = rest;

    const __bf16* __restrict__ Ab = (DUAL && branch) ? A1 : A0;
    const __bf16* __restrict__ Bb = (DUAL && branch) ? B1 : B0;

    const int w = tid >> 6;
    const int lane = tid & 63;

    // A staging: per gl_lds call 256 thr x 16B = 4KB = 64 rows x 64B.
    const int srow = tid >> 2;                      // 0..63 per call
    const int scol = ((tid & 3) << 4) ^ (((tid >> 3) & 3) << 4);
    const char* gA = (const char*)Ab + (size_t)(bm * 256 + srow) * LDA + scol;
    const char* gB = (const char*)Bb + (size_t)(bn * 128 + srow) * LDB + scol;

    auto stageA4 = [&](int kt, int buf) {           // 4 gl_lds = 16KB A tile
        const size_t ko = (size_t)kt * 64;
        char* d = ldsbuf + buf * BUFSZ + w * 1024;  // wave-uniform dest
        gl_lds16(gA + ko,             d);
        gl_lds16(gA + ko +  64 * LDA, d + 4096);
        gl_lds16(gA + ko + 128 * LDA, d + 8192);
        gl_lds16(gA + ko + 192 * LDA, d + 12288);
    };
    auto stageT = [&](int kt, int buf) {            // full tile (L0 path)
        const size_t ko = (size_t)kt * 64;
        char* d = ldsbuf + buf * BUFSZ + w * 1024;
        gl_lds16(gA + ko,             d);
        gl_lds16(gA + ko +  64 * LDA, d + 4096);
        gl_lds16(gA + ko + 128 * LDA, d + 8192);
        gl_lds16(gA + ko + 192 * LDA, d + 12288);
        gl_lds16(gB + ko,             d + 16384);
        gl_lds16(gB + ko +  64 * LDB, d + 20480);
    };

    // fragment read addressing (proven swizzle pair; 0 conflicts)
    const int wm = w >> 1, wn = w & 1;              // 2 x 2 waves
    const int lm = lane & 15, lq = lane >> 4;
    const int swz = ((lm >> 1) & 3) << 4;
    const int rA = (wm * 128 + lm) * 64 + ((lq * 16) ^ swz);
    const int rB = 16384 + (wn * 64 + lm) * 64 + ((lq * 16) ^ swz);

    // B direct: preshuffled fragment base per ni (col16 = bn*8 + wn*4 + ni)
    const char* pB[4];
#pragma unroll
    for (int ni = 0; ni < 4; ++ni)
        pB[ni] = (const char*)Bb +
                 (size_t)(bn * 8 + wn * 4 + ni) * 32768 + (size_t)lane * 16;

    f32x4 acc[4][8];                                // [ni][mi] (transposed)
    const f32x4 zero = {0.0f, 0.0f, 0.0f, 0.0f};
#pragma unroll
    for (int i = 0; i < 4; ++i)
#pragma unroll
        for (int j = 0; j < 8; ++j) acc[i][j] = zero;

    bf16x8 b0[4], b1[4];
    auto loadB = [&](int kt, bf16x8* bb) {
        MEMFENCE;
#pragma unroll
        for (int ni = 0; ni < 4; ++ni)
            bb[ni] = *(const bf16x8*)(pB[ni] + (size_t)kt * 1024);
        MEMFENCE;
    };

    // BD body: A ds_reads -> lgkm(0) -> barrier -> stage A(kt+2) -> 32 MFMA
    auto bodyBD = [&](int kt, int buf, bf16x8* bcur, bool dostage) {
        const char* Lb = ldsbuf + buf * BUFSZ;
        MEMFENCE;
        bf16x8 a[8];
#pragma unroll
        for (int mi = 0; mi < 8; ++mi)
            a[mi] = *(const bf16x8*)(Lb + rA + mi * 1024);
        MEMFENCE;
        __builtin_amdgcn_s_waitcnt(0xC07F);         // lgkmcnt(0)
        MEMFENCE;
        __builtin_amdgcn_s_barrier();               // all waves' A reads done
        MEMFENCE;
        if (dostage) stageA4(kt + 2, buf);
        MEMFENCE;
        __builtin_amdgcn_s_setprio(1);
#pragma unroll
        for (int ni = 0; ni < 4; ++ni)
#pragma unroll
            for (int mi = 0; mi < 8; ++mi)
                acc[ni][mi] = __builtin_amdgcn_mfma_f32_16x16x32_bf16(
                    bcur[ni], a[mi], acc[ni][mi], 0, 0, 0);
        __builtin_amdgcn_s_setprio(0);
    };

    // full-LDS body (L0): reads -> lgkm(0) -> barrier -> stage -> MFMA
    auto body2 = [&](int kt, int buf, bool dostage) {
        const char* Lb = ldsbuf + buf * BUFSZ;
        MEMFENCE;
        bf16x8 a[8], b[4];
#pragma unroll
        for (int ni = 0; ni < 4; ++ni)
            b[ni] = *(const bf16x8*)(Lb + rB + ni * 1024);
#pragma unroll
        for (int mi = 0; mi < 8; ++mi)
            a[mi] = *(const bf16x8*)(Lb + rA + mi * 1024);
        MEMFENCE;
        __builtin_amdgcn_s_waitcnt(0xC07F);
        MEMFENCE;
        __builtin_amdgcn_s_barrier();
        MEMFENCE;
        if (dostage) stageT(kt + 2, buf);
        MEMFENCE;
        __builtin_amdgcn_s_setprio(1);
#pragma unroll
        for (int ni = 0; ni < 4; ++ni)
#pragma unroll
            for (int mi = 0; mi < 8; ++mi)
                acc[ni][mi] = __builtin_amdgcn_mfma_f32_16x16x32_bf16(
                    b[ni], a[mi], acc[ni][mi], 0, 0, 0);
        __builtin_amdgcn_s_setprio(0);
    };

    if constexpr (NT == 32 && BD) {
        stageA4(0, 0); loadB(0, b0);                // issue: A0(4), B0(4)
        stageA4(1, 1); loadB(1, b1);                //        A1(4), B1(4)
        for (int g = 0; g < 15; ++g) {              // kt = 0..29
            WBAR(0xF78);                            // vmcnt(8): A(kt),B(kt) in
            bodyBD(2 * g + 0, 0, b0, true); loadB(2 * g + 2, b0);
            WBAR(0xF78);
            bodyBD(2 * g + 1, 1, b1, true); loadB(2 * g + 3, b1);
        }
        WBAR(0xF78); bodyBD(30, 0, b0, false);
        WBAR(0xF70); bodyBD(31, 1, b1, false);      // vmcnt(0)
    } else if constexpr (NT == 2) {                 // L0 (BD=false)
        stageT(0, 0);
        stageT(1, 1);
        WBAR(0xF76); body2(0, 0, false);            // vmcnt(6): buf0 landed
        WBAR(0xF70); body2(1, 1, false);            // vmcnt(0)
    }

    // ---- epilogue (transposed frag): lane (lm,lq), frag (ni,mi) holds
    // C[m = bm*256+wm*128+mi*16+lm][n = bn*128+wn*64+ni*16+lq*4+r]
    const int rowb = bm * 256 + wm * 128 + lm;
    const int nbase = bn * 128 + wn * 64 + lq * 4;

    if constexpr (MODE == 2) {
        const bool side = (bn >= (NBN >> 1));
        const float* __restrict__ bp = side ? bias1 : bias0;
        __bf16* __restrict__ Cw = side ? C1 : C0;
        const int nloc = nbase & 1023;
        f32x4 bv[4], p0v[4];
        const size_t p0base = (size_t)((bm << 1) | (lm & 1)) * 2048;
#pragma unroll
        for (int ni = 0; ni < 4; ++ni) {
            bv[ni]  = *(const f32x4*)&bp[nloc + ni * 16];
            p0v[ni] = *(const f32x4*)&P0[p0base + nbase + ni * 16];
        }
#pragma unroll
        for (int mi = 0; mi < 8; ++mi) {
            const int p1row = wm * 128 + mi * 16 + lm;
            f32x4 p1v[4];
#pragma unroll
            for (int ni = 0; ni < 4; ++ni)
                p1v[ni] = *(const f32x4*)&P1[(size_t)p1row * 2048 + nbase + ni * 16];
            MEMFENCE;
            const size_t rb = (size_t)(rowb + mi * 16) * 1024;
#pragma unroll
            for (int ni = 0; ni < 4; ++ni) {
                bf16x4 o;
#pragma unroll
                for (int r = 0; r < 4; ++r)
                    o[r] = (__bf16)gelu_f(acc[ni][mi][r] + bv[ni][r] +
                                          p0v[ni][r] + p1v[ni][r]);
                *(bf16x4*)&Cw[rb + nloc + ni * 16] = o;
            }
        }
        return;
    }

    const float* __restrict__ bp = (DUAL && branch) ? bias1 : bias0;
    f32x4 bv[4];
#pragma unroll
    for (int ni = 0; ni < 4; ++ni)
        bv[ni] = *(const f32x4*)&bp[nbase + ni * 16];

    if constexpr (MODE == 0) {
        __bf16* __restrict__ Cw = (DUAL && branch) ? C1 : C0;
#pragma unroll
        for (int mi = 0; mi < 8; ++mi) {
            const size_t rb = (size_t)(rowb + mi * 16) * 1024;
            bf16x4 res[4];
#pragma unroll
            for (int ni = 0; ni < 4; ++ni)
                res[ni] = *(const bf16x4*)&Ab[rb + nbase + ni * 16];
            MEMFENCE;
#pragma unroll
            for (int ni = 0; ni < 4; ++ni) {
                bf16x4 o;
#pragma unroll
                for (int r = 0; r < 4; ++r)
                    o[r] = (__bf16)(gelu_f(acc[ni][mi][r] + bv[ni][r]) +
                                    (float)res[ni][r]);
                *(bf16x4*)&Cw[rb + nbase + ni * 16] = o;
            }
        }
    } else if constexpr (MODE == 1) {
        const float* __restrict__ wb = (DUAL && branch) ? wout1 : wout0;
        f32x4 wv[4];
#pragma unroll
        for (int ni = 0; ni < 4; ++ni)
            wv[ni] = *(const f32x4*)&wb[nbase + ni * 16];
        float rd[8];
#pragma unroll
        for (int q = 0; q < 8; ++q) rd[q] = 0.0f;
#pragma unroll
        for (int mi = 0; mi < 8; ++mi) {
            const size_t rb = (size_t)(rowb + mi * 16) * 1024;
            bf16x4 res[4];
#pragma unroll
            for (int ni = 0; ni < 4; ++ni)
                res[ni] = *(const bf16x4*)&Ab[rb + nbase + ni * 16];
            MEMFENCE;
#pragma unroll
            for (int ni = 0; ni < 4; ++ni)
#pragma unroll
                for (int r = 0; r < 4; ++r) {
                    float v = gelu_f(acc[ni][mi][r] + bv[ni][r]) +
                              (float)res[ni][r];
                    rd[mi] += v * wv[ni][r];
                }
        }
#pragma unroll
        for (int mi = 0; mi < 8; ++mi) {
            rd[mi] += __shfl_xor(rd[mi], 16);
            rd[mi] += __shfl_xor(rd[mi], 32);
        }
        if (lq == 0) {
            float* __restrict__ db = (DUAL && branch) ? dot1 : dot0;
            float* dp = db + (size_t)(bn * 2 + wn) * 32768 + bm * 256 + wm * 128;
#pragma unroll
            for (int mi = 0; mi < 8; ++mi)
                dp[mi * 16 + lm] = rd[mi];
        }
    }
}

// ---------------------------------------------------------------------------
// finalize: sum 16 (bn,wn)-partials per row; block = (b,j), reduce over i
// ---------------------------------------------------------------------------
__global__ __launch_bounds__(128)
void finalize(const float* __restrict__ dot_e, const float* __restrict__ dot_f,
              const float* __restrict__ eb, const float* __restrict__ fb,
              const float* __restrict__ vec, float* __restrict__ out) {
    const int bj = blockIdx.x;
    const int bb = bj >> 7, jj = bj & 127;
    const int i = threadIdx.x;
    const int m = (i * 128 + jj) * 2 + bb;
    float e = eb[0], f = fb[0];
#pragma unroll
    for (int s = 0; s < 16; ++s) {
        e += dot_e[(size_t)s * 32768 + m];
        f += dot_f[(size_t)s * 32768 + m];
    }
    f *= (1.0f / 60.0f);
    float fx = f * vec[(size_t)m * 3 + 0];
    float fy = f * vec[(size_t)m * 3 + 1];
    float fz = f * vec[(size_t)m * 3 + 2];
#pragma unroll
    for (int off = 32; off > 0; off >>= 1) {
        e  += __shfl_down(e, off);
        fx += __shfl_down(fx, off);
        fy += __shfl_down(fy, off);
        fz += __shfl_down(fz, off);
    }
    __shared__ float red[2][4];
    const int wv = i >> 6, lane = i & 63;
    if (lane == 0) { red[wv][0] = e; red[wv][1] = fx; red[wv][2] = fy; red[wv][3] = fz; }
    __syncthreads();
    if (i == 0) {
        atomicAdd(&out[bb], (red[0][0] + red[1][0]) * (1.0f / 3600.0f));
        float* fo = out + 2 + bj * 3;
        fo[0] = red[0][1] + red[1][1];
        fo[1] = red[0][2] + red[1][2];
        fo[2] = red[0][3] + red[1][3];
    }
}

// ---------------------------------------------------------------------------
extern "C" void kernel_launch(void* const* d_in, const int* in_sizes, int n_in,
                              void* d_out, int out_size, void* d_ws, size_t ws_size,
                              hipStream_t stream) {
    const float* x     = (const float*)d_in[0];
    const float* dist  = (const float*)d_in[1];
    const float* vec   = (const float*)d_in[2];
    const float* rbfW  = (const float*)d_in[4];
    const float* rbf_b = (const float*)d_in[5];
    const float* eWin  = (const float*)d_in[6];
    const float* ebin  = (const float*)d_in[7];
    const float* eWh   = (const float*)d_in[8];
    const float* ebh   = (const float*)d_in[9];
    const float* eWout = (const float*)d_in[10];
    const float* ebout = (const float*)d_in[11];
    const float* fWin  = (const float*)d_in[12];
    const float* fbin  = (const float*)d_in[13];
    const float* fWh   = (const float*)d_in[14];
    const float* fbh   = (const float*)d_in[15];
    const float* fWout = (const float*)d_in[16];
    const float* fbout = (const float*)d_in[17];
    float* out = (float*)d_out;

    // workspace carve (3-slab, ~234 MB)
    char* p = (char*)d_ws;
    __bf16* WinTcat = (__bf16*)p;
    __bf16* eWinT = WinTcat;          p += (size_t)1024 * 1536 * 2;
    __bf16* fWinT = (__bf16*)p;       p += (size_t)1024 * 1536 * 2;
    __bf16* eWhT0 = (__bf16*)p;       p += (size_t)3 * 1024 * 1024 * 2;  // SHUFFLED
    __bf16* fWhT0 = (__bf16*)p;       p += (size_t)3 * 1024 * 1024 * 2;  // SHUFFLED
    __bf16* xb  = (__bf16*)p;         p += (size_t)256 * 512 * 2;
    __bf16* M1  = (__bf16*)p;         p += (size_t)128 * 512 * 2;
    __bf16* WgT = (__bf16*)p;         p += (size_t)2048 * 128 * 2;
    __bf16* G   = (__bf16*)p;         p += (size_t)32768 * 64 * 2;
    float* P0   = (float*)p;          p += (size_t)256 * 2048 * 4;
    float* P1   = (float*)p;          p += (size_t)256 * 2048 * 4;
    float* dot_e = (float*)p;         p += (size_t)16 * 32768 * 4;
    float* dot_f = (float*)p;         p += (size_t)16 * 32768 * 4;
    const size_t SLAB = (size_t)32768 * 1024 * 2;   // 64 MB
    __bf16* he0 = (__bf16*)p;         p += SLAB;
    __bf16* hf0 = (__bf16*)p;         p += SLAB;
    __bf16* hA  = (__bf16*)p;         p += SLAB;    // shared ping-pong slab

    // merged prep: build_G | x->xb | build_M1 | zero_out
    prep_all<<<dim3(1284), dim3(256), 0, stream>>>(
        dist, G, x, xb, rbfW, rbf_b, M1, out);
    // merged transposes: Win [N][K] (z 0..1) + Wh SHUFFLED (z 2..7)
    transpose_all<<<dim3(24, 16, 8), dim3(256), 0, stream>>>(
        eWin, fWin, eWinT, fWinT, eWh, fWh, eWhT0, fWhT0);

    const dim3 blk(256);
    // P0|P1 merged: x(256x512) @ Win[0:512) / [512:1024) -> f32 (256x2048)
    gemm_k<16, 16, 3, true, 3, false><<<dim3(64), blk, 0, stream>>>(
        xb, xb, WinTcat, WinTcat + 512, 1024, 3072, 2048,
        nullptr, nullptr, nullptr, nullptr, P0, P1,
        nullptr, nullptr, nullptr, nullptr, nullptr, nullptr);
    // WgT(2048x128) = WinTcat[:,1024:1536] @ M1^T (bf16 raw)
    gemm_k<16, 1, 4, false, 3, false><<<dim3(16), blk, 0, stream>>>(
        WinTcat + 1024, nullptr, M1, nullptr, 3072, 1024, 128,
        nullptr, nullptr, WgT, nullptr, nullptr, nullptr,
        nullptr, nullptr, nullptr, nullptr, nullptr, nullptr);

    // layer 0 (full-LDS path): he0|hf0 = gelu(G @ WgT + bias + P0 + P1)
    gemm256<2, false, 16, 2, 128, 256, false><<<dim3(2048), blk, 0, stream>>>(
        G, nullptr, WgT, nullptr, ebin, fbin, he0, hf0,
        nullptr, nullptr, nullptr, nullptr, P0, P1);

    // hidden layers, branch-serial, B-DIRECT (shuffled Wh): grid 1024
    gemm256<0, false, 8, 32, 2048, 2048, true><<<dim3(1024), blk, 0, stream>>>(
        he0, nullptr, eWhT0, nullptr, ebh + 0, nullptr,
        hA, nullptr, nullptr, nullptr, nullptr, nullptr, nullptr, nullptr);
    gemm256<0, false, 8, 32, 2048, 2048, true><<<dim3(1024), blk, 0, stream>>>(
        hA, nullptr, eWhT0 + (size_t)1048576, nullptr, ebh + 1024, nullptr,
        he0, nullptr, nullptr, nullptr, nullptr, nullptr, nullptr, nullptr);
    gemm256<0, false, 8, 32, 2048, 2048, true><<<dim3(1024), blk, 0, stream>>>(
        hf0, nullptr, fWhT0, nullptr, fbh + 0, nullptr,
        hA, nullptr, nullptr, nullptr, nullptr, nullptr, nullptr, nullptr);
    gemm256<0, false, 8, 32, 2048, 2048, true><<<dim3(1024), blk, 0, stream>>>(
        hA, nullptr, fWhT0 + (size_t)1048576, nullptr, fbh + 1024, nullptr,
        hf0, nullptr, nullptr, nullptr, nullptr, nullptr, nullptr, nullptr);
    // merged DUAL head, B-DIRECT: grid 2048
    gemm256<1, true, 8, 32, 2048, 2048, true><<<dim3(2048), blk, 0, stream>>>(
        he0, hf0, eWhT0 + (size_t)2 * 1048576, fWhT0 + (size_t)2 * 1048576,
        ebh + 2048, fbh + 2048, nullptr, nullptr,
        eWout, fWout, dot_e, dot_f, nullptr, nullptr);

    finalize<<<dim3(256), dim3(128), 0, stream>>>(dot_e, dot_f, ebout, fbout, vec, out);
}